// Round 1
// 246.928 us; speedup vs baseline: 1.0657x; 1.0657x over previous
//
#include <hip/hip_runtime.h>
#include <stdint.h>

#define M_DIM 16384
#define K_DIM 1024
#define N_DIM 4096
#define BM 128           // fallback tile
#define BN 128
#define LDSP 40          // fallback-path pad

#define TILE_ELEMS (128 * K_DIM)      // 131072 bf16 per 128-row packed tile
#define SLAB_ELEMS (128 * 32)         // 4096 bf16 per (tile, s) slab
#define CPAD 516                       // convert LDS row stride (dwords), b128-aligned

// ---- 8-phase GEMM geometry -------------------------------------------------
#define GBM 256
#define GBN 256
#define CHUNK 4096          // elems per 8 KB (tile,slab) chunk == SLAB_ELEMS
#define BUFE  (8 * CHUNK)   // 32768 elems per LDS K-tile buffer (64 KB)

typedef __bf16 bf16;
typedef __attribute__((ext_vector_type(8))) __bf16 bf16x8;
typedef __attribute__((ext_vector_type(4))) float f32x4;

// round-to-nearest-even fp32 -> bf16, packed two at a time (no NaN inputs)
__device__ __forceinline__ uint32_t pack2_bf16(float a, float b) {
    uint32_t ua = __float_as_uint(a);
    uint32_t ub = __float_as_uint(b);
    ua += 0x7fffu + ((ua >> 16) & 1u);
    ub += 0x7fffu + ((ub >> 16) & 1u);
    return (ua >> 16) | (ub & 0xffff0000u);
}

// ---- convert fp32 -> bf16 + repack into MFMA-fragment order (unchanged) ----
// Packed layout per 128-row tile: [s:32][rb:8][lane:64][j:8], lane = q*16+lrow,
// src row = rb*16 + lrow, src col = s*32 + q*8 + j.
__global__ __launch_bounds__(256) void convert_pack_kernel(
    const float* __restrict__ x, const float* __restrict__ w,
    bf16* __restrict__ xp, bf16* __restrict__ wp, float* __restrict__ out)
{
    int g = blockIdx.x;
    const int t = threadIdx.x;
    if (g < (M_DIM / 256)) out[g * 256 + t] = 0.f;   // 64 blocks zero out[]

    const float* src;
    bf16* dst;
    if (g < (M_DIM / 16)) {
        src = x + (size_t)g * 16 * K_DIM;  dst = xp;
    } else {
        g -= M_DIM / 16;
        src = w + (size_t)g * 16 * K_DIM;  dst = wp;
    }
    const int tile = g >> 3;
    const int rb   = g & 7;

    __shared__ uint32_t ls[16 * CPAD];   // ~33 KB

    #pragma unroll
    for (int i = 0; i < 16; ++i) {
        float4 v = ((const float4*)src)[i * 256 + t];
        uint2 d;
        d.x = pack2_bf16(v.x, v.y);
        d.y = pack2_bf16(v.z, v.w);
        *(uint2*)&ls[i * CPAD + t * 2] = d;
    }
    __syncthreads();

    const int wv = t >> 6, l = t & 63;
    const int lrow = l & 15, q = l >> 4;
    uint4* dst4 = (uint4*)(dst + (size_t)tile * TILE_ELEMS);
    #pragma unroll
    for (int it = 0; it < 8; ++it) {
        const int s = wv + it * 4;
        uint4 v = *(const uint4*)&ls[lrow * CPAD + s * 16 + q * 4];
        dst4[(s * 8 + rb) * 64 + l] = v;
    }
}

// ---- 256x256 8-phase double-buffered LDS GEMM (T3+T4+T5, m201-style) -------
// Pre-packed fragment layout => linear global_load_lds staging AND contiguous
// conflict-free ds_read_b128 fragment reads (no swizzle needed).
// Sync plan: stage order per K-tile = A-s0, B-s0, A-s1, B-s1 (2 chunks/phase);
// vmcnt(4) at phases q1/q3 retires exactly the 4 oldest loads (the chunks
// consumed next) while the newest 4 stay in flight across the barrier.

#define BARRIER() do { asm volatile("" ::: "memory"); \
                       __builtin_amdgcn_s_barrier();  \
                       asm volatile("" ::: "memory"); } while (0)
#define VMCNT4() asm volatile("s_waitcnt vmcnt(4)" ::: "memory")
#define VMCNT0() asm volatile("s_waitcnt vmcnt(0)" ::: "memory")

#define STAGE16(ldsOff, gsrc) \
    __builtin_amdgcn_global_load_lds( \
        (const __attribute__((address_space(1))) unsigned int*)(gsrc), \
        (__attribute__((address_space(3))) unsigned int*)&sm[(ldsOff) + w * 512], \
        16, 0, 0)

#define LDA4(sH, IB) do { \
    Af[0] = *(const bf16x8*)&sm[pO + (sH) * 8192 + aBase + ((IB) + 0) * 512]; \
    Af[1] = *(const bf16x8*)&sm[pO + (sH) * 8192 + aBase + ((IB) + 1) * 512]; \
    Af[2] = *(const bf16x8*)&sm[pO + (sH) * 8192 + aBase + ((IB) + 2) * 512]; \
    Af[3] = *(const bf16x8*)&sm[pO + (sH) * 8192 + aBase + ((IB) + 3) * 512]; \
} while (0)

#define LDB4(sH) do { \
    Bf[0] = *(const bf16x8*)&sm[pO + (sH) * 8192 + bBase + 0 * 512]; \
    Bf[1] = *(const bf16x8*)&sm[pO + (sH) * 8192 + bBase + 1 * 512]; \
    Bf[2] = *(const bf16x8*)&sm[pO + (sH) * 8192 + bBase + 2 * 512]; \
    Bf[3] = *(const bf16x8*)&sm[pO + (sH) * 8192 + bBase + 3 * 512]; \
} while (0)

#define MFMA16(IB) do { \
    __builtin_amdgcn_s_setprio(1); \
    _Pragma("unroll") \
    for (int ii = 0; ii < 4; ++ii) \
        _Pragma("unroll") \
        for (int jj = 0; jj < 4; ++jj) \
            acc[(IB) + ii][jj] = __builtin_amdgcn_mfma_f32_16x16x32_bf16( \
                Af[ii], Bf[jj], acc[(IB) + ii][jj], 0, 0, 0); \
    __builtin_amdgcn_s_setprio(0); \
} while (0)

// One K-tile (BK=64 = slabs 2T, 2T+1 from buffer P), staging tile T+1 if STG.
#define TILE_BODY(T, P, STG) do { \
    const int pO  = (P) * BUFE; \
    const int pnO = ((P) ^ 1) * BUFE; \
    /* q0: frags (s0, i0-3) + all B(s0); stage A-s0 of next tile */ \
    LDA4(0, 0); LDB4(0); \
    if (STG) { STAGE16(pnO + 0 * CHUNK, Ag + 0 * TILE_ELEMS + (size_t)(2 * (T) + 2) * CHUNK + toff); \
               STAGE16(pnO + 1 * CHUNK, Ag + 1 * TILE_ELEMS + (size_t)(2 * (T) + 2) * CHUNK + toff); } \
    BARRIER(); MFMA16(0); BARRIER(); \
    /* q1: frags (s0, i4-7); stage B-s0 */ \
    LDA4(0, 4); \
    if (STG) { STAGE16(pnO + 4 * CHUNK, Bg + 0 * TILE_ELEMS + (size_t)(2 * (T) + 2) * CHUNK + toff); \
               STAGE16(pnO + 5 * CHUNK, Bg + 1 * TILE_ELEMS + (size_t)(2 * (T) + 2) * CHUNK + toff); } \
    BARRIER(); MFMA16(4); \
    if (STG) { VMCNT4(); } else { VMCNT0(); }   /* s1 of current buffer landed */ \
    BARRIER(); \
    /* q2: frags (s1, i0-3) + all B(s1); stage A-s1 */ \
    LDA4(1, 0); LDB4(1); \
    if (STG) { STAGE16(pnO + 2 * CHUNK, Ag + 0 * TILE_ELEMS + (size_t)(2 * (T) + 3) * CHUNK + toff); \
               STAGE16(pnO + 3 * CHUNK, Ag + 1 * TILE_ELEMS + (size_t)(2 * (T) + 3) * CHUNK + toff); } \
    BARRIER(); MFMA16(0); BARRIER(); \
    /* q3: frags (s1, i4-7); stage B-s1 */ \
    LDA4(1, 4); \
    if (STG) { STAGE16(pnO + 6 * CHUNK, Bg + 0 * TILE_ELEMS + (size_t)(2 * (T) + 3) * CHUNK + toff); \
               STAGE16(pnO + 7 * CHUNK, Bg + 1 * TILE_ELEMS + (size_t)(2 * (T) + 3) * CHUNK + toff); } \
    BARRIER(); MFMA16(4); \
    if (STG) { VMCNT4(); }                       /* s0 of next buffer landed */ \
    BARRIER(); \
} while (0)

__global__ __launch_bounds__(512, 2) void gemm_pool_8phase_kernel(
    const bf16* __restrict__ xp, const bf16* __restrict__ wp,
    const float* __restrict__ bias, float* __restrict__ out)
{
    __shared__ bf16 sm[2 * BUFE];   // 128 KB

    const int b  = blockIdx.x;
    const int bx = b & (N_DIM / GBN - 1);   // 0..15  (B tile; 512 KB, L2-hot)
    const int by = b >> 4;                  // 0..63

    const int tid  = threadIdx.x;
    const int lane = tid & 63;
    const int w    = tid >> 6;      // wave 0..7
    const int wm   = w >> 2;        // M half  (0..1): rows wm*128..+127 = packed tile 2by+wm
    const int wn   = w & 3;         // N quarter (0..3): cols wn*64..+63
    const int lr   = lane & 15;
    const int quad = lane >> 4;
    const int toff = tid * 8;       // staging: elem offset within a chunk

    const bf16* __restrict__ Ag = xp + (size_t)(2 * by) * TILE_ELEMS;
    const bf16* __restrict__ Bg = wp + (size_t)(2 * bx) * TILE_ELEMS;

    // LDS chunk map per buffer: c = sH*2 + tile (A), 4 + sH*2 + tile (B)
    const int aBase = wm * CHUNK + lane * 8;
    const int bBase = 4 * CHUNK + (wn >> 1) * CHUNK + (wn & 1) * 2048 + lane * 8;

    f32x4 acc[8][4] = {};
    bf16x8 Af[4], Bf[4];

    // prologue: stage K-tile 0 (slabs 0,1) into buffer 0, consumption order
    STAGE16(0 * CHUNK, Ag + 0 * TILE_ELEMS + toff);
    STAGE16(1 * CHUNK, Ag + 1 * TILE_ELEMS + toff);
    STAGE16(4 * CHUNK, Bg + 0 * TILE_ELEMS + toff);
    STAGE16(5 * CHUNK, Bg + 1 * TILE_ELEMS + toff);
    STAGE16(2 * CHUNK, Ag + 0 * TILE_ELEMS + CHUNK + toff);
    STAGE16(3 * CHUNK, Ag + 1 * TILE_ELEMS + CHUNK + toff);
    STAGE16(6 * CHUNK, Bg + 0 * TILE_ELEMS + CHUNK + toff);
    STAGE16(7 * CHUNK, Bg + 1 * TILE_ELEMS + CHUNK + toff);
    VMCNT4(); BARRIER();            // s0 chunks visible; s1 still in flight

    #pragma unroll
    for (int t = 0; t < 15; ++t) {
        const int p = t & 1;
        TILE_BODY(t, p, 1);
    }
    TILE_BODY(15, 1, 0);            // tail: no staging, q1 drains to vmcnt(0)

    // fused epilogue: +bias, maxpool4 along N, row-sum, atomic out
    // C/D layout: col = lane&15, row = quad*4 + reg  [m89/m91]
    float bv[4];
    #pragma unroll
    for (int j = 0; j < 4; ++j)
        bv[j] = bias[bx * GBN + wn * 64 + j * 16 + lr];

    #pragma unroll
    for (int i = 0; i < 8; ++i) {
        float rs[4] = {0.f, 0.f, 0.f, 0.f};
        #pragma unroll
        for (int j = 0; j < 4; ++j) {
            #pragma unroll
            for (int r = 0; r < 4; ++r) {
                float v = acc[i][j][r] + bv[j];
                v = fmaxf(v, __shfl_xor(v, 1, 64));   // pool group = 4 adjacent cols
                v = fmaxf(v, __shfl_xor(v, 2, 64));
                rs[r] += v;
            }
        }
        #pragma unroll
        for (int r = 0; r < 4; ++r) {
            rs[r] += __shfl_xor(rs[r], 4, 64);        // one max per group summed
            rs[r] += __shfl_xor(rs[r], 8, 64);
        }
        if (lr == 0) {
            const int row = by * GBM + wm * 128 + i * 16 + quad * 4;
            #pragma unroll
            for (int r = 0; r < 4; ++r)
                atomicAdd(&out[row + r], rs[r] * 0.5f);
        }
    }
}

// ---- fallback (round-1 kernel) if ws too small -----------------------------
__global__ __launch_bounds__(256) void fused_linear_pool_kernel(
    const float* __restrict__ x, const float* __restrict__ wt,
    const float* __restrict__ bias, float* __restrict__ out)
{
    __shared__ uint32_t sA[BM * LDSP / 2];
    __shared__ uint32_t sB[BN * LDSP / 2];

    const int tid = threadIdx.x;
    const int bx = blockIdx.x;
    const int by = blockIdx.y;

    const float* Abase = x  + (size_t)by * BM * K_DIM;
    const float* Bbase = wt + (size_t)bx * BN * K_DIM;

    const int lane = tid & 63;
    const int wave = tid >> 6;
    const int wm = wave >> 1;
    const int wn = wave & 1;
    const int lr = lane & 15;
    const int quad = lane >> 4;

    const int srow  = tid >> 2;
    const int scol  = (tid & 3) * 8;
    const int swidx = (tid & 3) * 4;

    f32x4 acc[4][4] = {};

    for (int kt = 0; kt < K_DIM; kt += 32) {
        #pragma unroll
        for (int p = 0; p < 2; ++p) {
            const int r = srow + p * 64;
            const float4* ga = (const float4*)(Abase + (size_t)r * K_DIM + kt + scol);
            const float4* gb = (const float4*)(Bbase + (size_t)r * K_DIM + kt + scol);
            float4 a0 = ga[0], a1 = ga[1], b0 = gb[0], b1 = gb[1];
            uint4 wa;
            wa.x = pack2_bf16(a0.x, a0.y); wa.y = pack2_bf16(a0.z, a0.w);
            wa.z = pack2_bf16(a1.x, a1.y); wa.w = pack2_bf16(a1.z, a1.w);
            *(uint4*)&sA[r * (LDSP / 2) + swidx] = wa;
            uint4 wbv;
            wbv.x = pack2_bf16(b0.x, b0.y); wbv.y = pack2_bf16(b0.z, b0.w);
            wbv.z = pack2_bf16(b1.x, b1.y); wbv.w = pack2_bf16(b1.z, b1.w);
            *(uint4*)&sB[r * (LDSP / 2) + swidx] = wbv;
        }
        __syncthreads();

        bf16x8 af[4], bfr[4];
        #pragma unroll
        for (int i = 0; i < 4; ++i)
            af[i] = *(const bf16x8*)((const bf16*)sA + (wm * 64 + i * 16 + lr) * LDSP + quad * 8);
        #pragma unroll
        for (int j = 0; j < 4; ++j)
            bfr[j] = *(const bf16x8*)((const bf16*)sB + (wn * 64 + j * 16 + lr) * LDSP + quad * 8);

        #pragma unroll
        for (int i = 0; i < 4; ++i)
            #pragma unroll
            for (int j = 0; j < 4; ++j)
                acc[i][j] = __builtin_amdgcn_mfma_f32_16x16x32_bf16(af[i], bfr[j], acc[i][j], 0, 0, 0);
        __syncthreads();
    }

    float bv[4];
    #pragma unroll
    for (int j = 0; j < 4; ++j)
        bv[j] = bias[bx * BN + wn * 64 + j * 16 + lr];

    #pragma unroll
    for (int i = 0; i < 4; ++i) {
        float rsum[4] = {0.f, 0.f, 0.f, 0.f};
        #pragma unroll
        for (int j = 0; j < 4; ++j) {
            #pragma unroll
            for (int r = 0; r < 4; ++r) {
                float t = acc[i][j][r] + bv[j];
                t = fmaxf(t, __shfl_xor(t, 1, 64));
                t = fmaxf(t, __shfl_xor(t, 2, 64));
                t += __shfl_xor(t, 4, 64);
                t += __shfl_xor(t, 8, 64);
                rsum[r] += t;
            }
        }
        if (lr == 0) {
            const int row = by * BM + wm * 64 + i * 16 + quad * 4;
            #pragma unroll
            for (int r = 0; r < 4; ++r)
                atomicAdd(&out[row + r], rsum[r] * 0.5f);
        }
    }
}

extern "C" void kernel_launch(void* const* d_in, const int* in_sizes, int n_in,
                              void* d_out, int out_size, void* d_ws, size_t ws_size,
                              hipStream_t stream) {
    const float* x  = (const float*)d_in[0];
    const float* wt = (const float*)d_in[1];
    const float* bs = (const float*)d_in[2];
    float* out = (float*)d_out;

    const size_t xe = (size_t)M_DIM * K_DIM;
    const size_t we = (size_t)N_DIM * K_DIM;
    const size_t need = (xe + we) * sizeof(bf16);  // ~42 MB

    if (ws_size >= need) {
        bf16* xp = (bf16*)d_ws;
        bf16* wp = xp + xe;
        const int nconv = (M_DIM / 16) + (N_DIM / 16);   // 1024 + 256 = 1280
        convert_pack_kernel<<<nconv, 256, 0, stream>>>(x, wt, xp, wp, out);
        gemm_pool_8phase_kernel<<<(M_DIM / GBM) * (N_DIM / GBN), 512, 0, stream>>>(xp, wp, bs, out);
    } else {
        hipMemsetAsync(out, 0, (size_t)out_size * sizeof(float), stream);
        dim3 grid(N_DIM / BN, M_DIM / BM);
        fused_linear_pool_kernel<<<grid, 256, 0, stream>>>(x, wt, bs, out);
    }
}

// Round 2
// 242.599 us; speedup vs baseline: 1.0847x; 1.0178x over previous
//
#include <hip/hip_runtime.h>
#include <stdint.h>

#define M_DIM 16384
#define K_DIM 1024
#define N_DIM 4096
#define BM 128           // fallback tile
#define BN 128
#define LDSP 40          // fallback-path pad

#define TILE_ELEMS (128 * K_DIM)      // 131072 bf16 per 128-row packed tile
#define CPAD 516                       // convert LDS row stride (dwords)

// ---- ring GEMM geometry ----------------------------------------------------
#define GBM 256
#define GBN 256
#define NSLAB 32            // K_DIM / 32
#define SLOT_E 16384        // elems per ring slot: 4 chunks x 4096 (32 KB)

typedef __bf16 bf16;
typedef __attribute__((ext_vector_type(8))) __bf16 bf16x8;
typedef __attribute__((ext_vector_type(4))) float f32x4;

// round-to-nearest-even fp32 -> bf16, packed two at a time (no NaN inputs)
__device__ __forceinline__ uint32_t pack2_bf16(float a, float b) {
    uint32_t ua = __float_as_uint(a);
    uint32_t ub = __float_as_uint(b);
    ua += 0x7fffu + ((ua >> 16) & 1u);
    ub += 0x7fffu + ((ub >> 16) & 1u);
    return (ua >> 16) | (ub & 0xffff0000u);
}

// ---- convert fp32 -> bf16 + repack into MFMA-fragment order (unchanged) ----
// Packed layout per 128-row tile: [s:32][rb:8][lane:64][j:8], lane = q*16+lrow,
// src row = rb*16 + lrow, src col = s*32 + q*8 + j.
__global__ __launch_bounds__(256) void convert_pack_kernel(
    const float* __restrict__ x, const float* __restrict__ w,
    bf16* __restrict__ xp, bf16* __restrict__ wp, float* __restrict__ out)
{
    int g = blockIdx.x;
    const int t = threadIdx.x;
    if (g < (M_DIM / 256)) out[g * 256 + t] = 0.f;   // 64 blocks zero out[]

    const float* src;
    bf16* dst;
    if (g < (M_DIM / 16)) {
        src = x + (size_t)g * 16 * K_DIM;  dst = xp;
    } else {
        g -= M_DIM / 16;
        src = w + (size_t)g * 16 * K_DIM;  dst = wp;
    }
    const int tile = g >> 3;
    const int rb   = g & 7;

    __shared__ uint32_t ls[16 * CPAD];   // ~33 KB

    #pragma unroll
    for (int i = 0; i < 16; ++i) {
        float4 v = ((const float4*)src)[i * 256 + t];
        uint2 d;
        d.x = pack2_bf16(v.x, v.y);
        d.y = pack2_bf16(v.z, v.w);
        *(uint2*)&ls[i * CPAD + t * 2] = d;
    }
    __syncthreads();

    const int wv = t >> 6, l = t & 63;
    const int lrow = l & 15, q = l >> 4;
    uint4* dst4 = (uint4*)(dst + (size_t)tile * TILE_ELEMS);
    #pragma unroll
    for (int it = 0; it < 8; ++it) {
        const int s = wv + it * 4;
        uint4 v = *(const uint4*)&ls[lrow * CPAD + s * 16 + q * 4];
        dst4[(s * 8 + rb) * 64 + l] = v;
    }
}

// ---- 256x256 ring-buffer GEMM: reg ping-pong, 1 barrier / 32 MFMA ----------
// BK=32 slabs; 4-slot LDS ring (32 KB each, 128 KB total); stage 2 slabs ahead.
// Per slab: {stage A(s+2); read Ahi(s); MFMA(Alo,B)(s);
//            stage B(s+2); vmcnt(4); barrier; read Alo/B(s+1); MFMA(Ahi,B)(s)}.
// ds_reads for the next burst issue BEFORE the current MFMA burst -> compiler
// emits counted lgkm waits; LDS service hides under the matrix pipe.
// vmcnt(4): outstanding = 4 (slab s+1) + 4 (slab s+2); retires s+1 only.

#define BAR() do { asm volatile("" ::: "memory"); \
                   __builtin_amdgcn_s_barrier();  \
                   asm volatile("" ::: "memory"); } while (0)
#define VMCNT4() asm volatile("s_waitcnt vmcnt(4)" ::: "memory")
#define VMCNT0() asm volatile("s_waitcnt vmcnt(0)" ::: "memory")

// stage one 8 KB chunk: wave w writes its 1 KB slice (lane x 16 B, linear)
#define STG(sl, ch, gsrc) \
    __builtin_amdgcn_global_load_lds( \
        (const __attribute__((address_space(1))) unsigned int*)(gsrc), \
        (__attribute__((address_space(3))) unsigned int*)&sm[(((sl) & 3) * SLOT_E) + (ch) * 4096 + w * 512], \
        16, 0, 0)

#define STG_A(t) do { STG(t, 0, Ag + (size_t)(t) * 4096 + toff); \
                      STG(t, 1, Ag + TILE_ELEMS + (size_t)(t) * 4096 + toff); } while (0)
#define STG_B(t) do { STG(t, 2, Bg + (size_t)(t) * 4096 + toff); \
                      STG(t, 3, Bg + TILE_ELEMS + (size_t)(t) * 4096 + toff); } while (0)

#define RD4(dst, base) do { \
    _Pragma("unroll") \
    for (int _i = 0; _i < 4; ++_i) \
        dst[_i] = *(const bf16x8*)&sm[(base) + _i * 512]; \
} while (0)

#define MFMA16X(Aset, Bset, IB) do { \
    __builtin_amdgcn_s_setprio(1); \
    _Pragma("unroll") \
    for (int ii = 0; ii < 4; ++ii) \
        _Pragma("unroll") \
        for (int jj = 0; jj < 4; ++jj) \
            acc[(IB) + ii][jj] = __builtin_amdgcn_mfma_f32_16x16x32_bf16( \
                Aset[ii], Bset[jj], acc[(IB) + ii][jj], 0, 0, 0); \
    __builtin_amdgcn_s_setprio(0); \
} while (0)

// CUR/NXT are token-pasted register-set suffixes (A or B)
#define SLAB(s, CUR, NXT) do { \
    if ((s) + 2 < NSLAB) STG_A((s) + 2); \
    RD4(Ahi, (((s) & 3) * SLOT_E) + aOff + 2048); \
    MFMA16X(Alo##CUR, Bv##CUR, 0); \
    if ((s) + 2 < NSLAB) STG_B((s) + 2); \
    if ((s) == NSLAB - 2) { VMCNT0(); } else if ((s) < NSLAB - 2) { VMCNT4(); } \
    BAR(); \
    if ((s) + 1 < NSLAB) { \
        RD4(Alo##NXT, ((((s) + 1) & 3) * SLOT_E) + aOff); \
        RD4(Bv##NXT,  ((((s) + 1) & 3) * SLOT_E) + bOff); \
    } \
    MFMA16X(Ahi, Bv##CUR, 4); \
} while (0)

__global__ __launch_bounds__(512, 2) void gemm_pool_ring_kernel(
    const bf16* __restrict__ xp, const bf16* __restrict__ wp,
    const float* __restrict__ bias, float* __restrict__ out)
{
    __shared__ bf16 sm[4 * SLOT_E];   // 128 KB

    const int b  = blockIdx.x;
    const int bx = b & (N_DIM / GBN - 1);   // 0..15
    const int by = b >> 4;                  // 0..63

    const int tid  = threadIdx.x;
    const int lane = tid & 63;
    const int w    = tid >> 6;      // wave 0..7
    const int wm   = w >> 2;        // M half: packed tile 2by+wm (rows wm*128..)
    const int wn   = w & 3;         // N quarter: cols wn*64..
    const int lr   = lane & 15;
    const int quad = lane >> 4;
    const int toff = tid * 8;       // staging: elem offset within a chunk

    const bf16* __restrict__ Ag = xp + (size_t)(2 * by) * TILE_ELEMS;
    const bf16* __restrict__ Bg = wp + (size_t)(2 * bx) * TILE_ELEMS;

    // ring-slot-relative fragment bases (elems)
    const int aOff = wm * 4096 + lane * 8;                             // chunks 0,1
    const int bOff = 8192 + (wn >> 1) * 4096 + (wn & 1) * 2048 + lane * 8; // chunks 2,3

    f32x4 acc[8][4] = {};
    bf16x8 AloA[4], AloB[4], Ahi[4], BvA[4], BvB[4];

    // prologue: stage slabs 0,1 (consumption order), wait slab 0, read phase-0 frags
    STG_A(0); STG_B(0);
    STG_A(1); STG_B(1);
    VMCNT4(); BAR();                 // slab 0 landed; slab 1 in flight
    RD4(AloA, aOff);                 // slot 0
    RD4(BvA,  bOff);

    #pragma unroll
    for (int sp = 0; sp < NSLAB / 2; ++sp) {
        SLAB(2 * sp,     A, B);
        SLAB(2 * sp + 1, B, A);
    }

    // fused epilogue: +bias, maxpool4 along N, row-sum, atomic out
    // C/D layout: col = lane&15, row = quad*4 + reg  [m89/m91]
    float bv[4];
    #pragma unroll
    for (int j = 0; j < 4; ++j)
        bv[j] = bias[bx * GBN + wn * 64 + j * 16 + lr];

    #pragma unroll
    for (int i = 0; i < 8; ++i) {
        float rs[4] = {0.f, 0.f, 0.f, 0.f};
        #pragma unroll
        for (int j = 0; j < 4; ++j) {
            #pragma unroll
            for (int r = 0; r < 4; ++r) {
                float v = acc[i][j][r] + bv[j];
                v = fmaxf(v, __shfl_xor(v, 1, 64));   // pool group = 4 adjacent cols
                v = fmaxf(v, __shfl_xor(v, 2, 64));
                rs[r] += v;
            }
        }
        #pragma unroll
        for (int r = 0; r < 4; ++r) {
            rs[r] += __shfl_xor(rs[r], 4, 64);        // one max per group summed
            rs[r] += __shfl_xor(rs[r], 8, 64);
        }
        if (lr == 0) {
            const int row = by * GBM + wm * 128 + i * 16 + quad * 4;
            #pragma unroll
            for (int r = 0; r < 4; ++r)
                atomicAdd(&out[row + r], rs[r] * 0.5f);
        }
    }
}

// ---- fallback (round-1 kernel) if ws too small -----------------------------
__global__ __launch_bounds__(256) void fused_linear_pool_kernel(
    const float* __restrict__ x, const float* __restrict__ wt,
    const float* __restrict__ bias, float* __restrict__ out)
{
    __shared__ uint32_t sA[BM * LDSP / 2];
    __shared__ uint32_t sB[BN * LDSP / 2];

    const int tid = threadIdx.x;
    const int bx = blockIdx.x;
    const int by = blockIdx.y;

    const float* Abase = x  + (size_t)by * BM * K_DIM;
    const float* Bbase = wt + (size_t)bx * BN * K_DIM;

    const int lane = tid & 63;
    const int wave = tid >> 6;
    const int wm = wave >> 1;
    const int wn = wave & 1;
    const int lr = lane & 15;
    const int quad = lane >> 4;

    const int srow  = tid >> 2;
    const int scol  = (tid & 3) * 8;
    const int swidx = (tid & 3) * 4;

    f32x4 acc[4][4] = {};

    for (int kt = 0; kt < K_DIM; kt += 32) {
        #pragma unroll
        for (int p = 0; p < 2; ++p) {
            const int r = srow + p * 64;
            const float4* ga = (const float4*)(Abase + (size_t)r * K_DIM + kt + scol);
            const float4* gb = (const float4*)(Bbase + (size_t)r * K_DIM + kt + scol);
            float4 a0 = ga[0], a1 = ga[1], b0 = gb[0], b1 = gb[1];
            uint4 wa;
            wa.x = pack2_bf16(a0.x, a0.y); wa.y = pack2_bf16(a0.z, a0.w);
            wa.z = pack2_bf16(a1.x, a1.y); wa.w = pack2_bf16(a1.z, a1.w);
            *(uint4*)&sA[r * (LDSP / 2) + swidx] = wa;
            uint4 wbv;
            wbv.x = pack2_bf16(b0.x, b0.y); wbv.y = pack2_bf16(b0.z, b0.w);
            wbv.z = pack2_bf16(b1.x, b1.y); wbv.w = pack2_bf16(b1.z, b1.w);
            *(uint4*)&sB[r * (LDSP / 2) + swidx] = wbv;
        }
        __syncthreads();

        bf16x8 af[4], bfr[4];
        #pragma unroll
        for (int i = 0; i < 4; ++i)
            af[i] = *(const bf16x8*)((const bf16*)sA + (wm * 64 + i * 16 + lr) * LDSP + quad * 8);
        #pragma unroll
        for (int j = 0; j < 4; ++j)
            bfr[j] = *(const bf16x8*)((const bf16*)sB + (wn * 64 + j * 16 + lr) * LDSP + quad * 8);

        #pragma unroll
        for (int i = 0; i < 4; ++i)
            #pragma unroll
            for (int j = 0; j < 4; ++j)
                acc[i][j] = __builtin_amdgcn_mfma_f32_16x16x32_bf16(af[i], bfr[j], acc[i][j], 0, 0, 0);
        __syncthreads();
    }

    float bv[4];
    #pragma unroll
    for (int j = 0; j < 4; ++j)
        bv[j] = bias[bx * BN + wn * 64 + j * 16 + lr];

    #pragma unroll
    for (int i = 0; i < 4; ++i) {
        float rsum[4] = {0.f, 0.f, 0.f, 0.f};
        #pragma unroll
        for (int j = 0; j < 4; ++j) {
            #pragma unroll
            for (int r = 0; r < 4; ++r) {
                float t = acc[i][j][r] + bv[j];
                t = fmaxf(t, __shfl_xor(t, 1, 64));
                t = fmaxf(t, __shfl_xor(t, 2, 64));
                t += __shfl_xor(t, 4, 64);
                t += __shfl_xor(t, 8, 64);
                rsum[r] += t;
            }
        }
        if (lr == 0) {
            const int row = by * BM + wm * 64 + i * 16 + quad * 4;
            #pragma unroll
            for (int r = 0; r < 4; ++r)
                atomicAdd(&out[row + r], rsum[r] * 0.5f);
        }
    }
}

extern "C" void kernel_launch(void* const* d_in, const int* in_sizes, int n_in,
                              void* d_out, int out_size, void* d_ws, size_t ws_size,
                              hipStream_t stream) {
    const float* x  = (const float*)d_in[0];
    const float* wt = (const float*)d_in[1];
    const float* bs = (const float*)d_in[2];
    float* out = (float*)d_out;

    const size_t xe = (size_t)M_DIM * K_DIM;
    const size_t we = (size_t)N_DIM * K_DIM;
    const size_t need = (xe + we) * sizeof(bf16);  // ~42 MB

    if (ws_size >= need) {
        bf16* xp = (bf16*)d_ws;
        bf16* wp = xp + xe;
        const int nconv = (M_DIM / 16) + (N_DIM / 16);   // 1024 + 256 = 1280
        convert_pack_kernel<<<nconv, 256, 0, stream>>>(x, wt, xp, wp, out);
        gemm_pool_ring_kernel<<<(M_DIM / GBM) * (N_DIM / GBN), 512, 0, stream>>>(xp, wp, bs, out);
    } else {
        hipMemsetAsync(out, 0, (size_t)out_size * sizeof(float), stream);
        dim3 grid(N_DIM / BN, M_DIM / BM);
        fused_linear_pool_kernel<<<grid, 256, 0, stream>>>(x, wt, bs, out);
    }
}